// Round 7
// baseline (185.204 us; speedup 1.0000x reference)
//
#include <hip/hip_runtime.h>

// SpatialEngram: out[b,o,i,j] = (table @ proj_w.T + proj_b)[idx[b,i,j]][o]
// where idx = trunc(mean_c(abs(3x3_sum(trunc(x*100)))%P))
//
// Round 7: fused structure (Round 4, best known 108 us) with ONE change:
//   plain cached float4 stores instead of __builtin_nontemporal_store.
//   A/B test: nt stores forfeit L2 write-combining of the 64-plane 16B-granular
//   write pattern; plain stores let L2 assemble large HBM bursts (the harness
//   fill kernels prove ~7 TB/s through L2 on this exact output buffer).

#define CH  32
#define HH  512
#define WW  512
#define EE  64
#define OUT 64
#define PP  10000

#define TWPX 256              // tile width in pixels (64 threads x 4 px)
#define HW   (HH * WW)

__global__ __launch_bounds__(256) void proj_table_kernel(
    const float* __restrict__ table, const float* __restrict__ pw,
    const float* __restrict__ pb, float* __restrict__ tp) {
  __shared__ float sW[EE * OUT];          // sW[e*64 + o] = pw[o*64 + e]
  const int t = threadIdx.x;              // 0..255
  for (int i = t; i < EE * OUT; i += 256) {
    int o = i >> 6, e = i & 63;
    sW[e * OUT + o] = pw[i];
  }
  __syncthreads();
  const int p = blockIdx.x * 4 + (t >> 6);
  const int o = t & 63;
  const float4* trow = (const float4*)(table + (size_t)p * EE);
  float s0 = pb[o], s1 = 0.f, s2 = 0.f, s3 = 0.f;
  #pragma unroll
  for (int e4 = 0; e4 < EE / 4; ++e4) {
    float4 tv = trow[e4];                 // wave-uniform per 64-lane group
    s0 = fmaf(tv.x, sW[(4 * e4 + 0) * OUT + o], s0);
    s1 = fmaf(tv.y, sW[(4 * e4 + 1) * OUT + o], s1);
    s2 = fmaf(tv.z, sW[(4 * e4 + 2) * OUT + o], s2);
    s3 = fmaf(tv.w, sW[(4 * e4 + 3) * OUT + o], s3);
  }
  tp[(size_t)p * OUT + o] = (s0 + s1) + (s2 + s3);
}

__device__ __forceinline__ int q3(float a, float b, float c) {
  // column sum of trunc(v*100) over 3 rows; (int) truncates toward zero
  return (int)(a * 100.0f) + (int)(b * 100.0f) + (int)(c * 100.0f);
}

__global__ __launch_bounds__(256) void engram_kernel(
    const float* __restrict__ x, const float* __restrict__ tp,
    float* __restrict__ out) {
  const int tx  = threadIdx.x;            // 0..63
  const int ty  = threadIdx.y;            // 0..3
  const int gx0 = blockIdx.x * TWPX;
  const int y   = blockIdx.y * 4 + ty;
  const int b   = blockIdx.z;
  const int x0  = gx0 + tx * 4;

  const int ym1 = max(y - 1, 0);
  const int yp1 = min(y + 1, HH - 1);
  const size_t rm1 = (size_t)ym1 * WW + x0;
  const size_t r0  = (size_t)y   * WW + x0;
  const size_t rp1 = (size_t)yp1 * WW + x0;

  const bool edge = (tx == 0) || (tx == 63);
  const int  ecol = (tx == 0) ? max(gx0 - 1, 0) : min(gx0 + TWPX, WW - 1);
  const size_t em1 = (size_t)ym1 * WW + ecol;
  const size_t e0  = (size_t)y   * WW + ecol;
  const size_t ep1 = (size_t)yp1 * WW + ecol;

  const float* xb = x + (size_t)b * CH * HW;

  int acc0 = 0, acc1 = 0, acc2 = 0, acc3 = 0;
  #pragma unroll 2
  for (int c = 0; c < CH; ++c) {
    const float* xc = xb + (size_t)c * HW;
    float4 a = *(const float4*)(xc + rm1);
    float4 m = *(const float4*)(xc + r0);
    float4 p = *(const float4*)(xc + rp1);

    int cs0 = q3(a.x, m.x, p.x);
    int cs1 = q3(a.y, m.y, p.y);
    int cs2 = q3(a.z, m.z, p.z);
    int cs3 = q3(a.w, m.w, p.w);

    int csl = __shfl(cs3, tx - 1, 64);    // junk for tx==0 (overwritten)
    int csr = __shfl(cs0, tx + 1, 64);    // junk for tx==63 (overwritten)
    if (edge) {
      int e = q3(xc[em1], xc[e0], xc[ep1]);
      if (tx == 0) csl = e; else csr = e;
    }

    int h0 = csl + cs0 + cs1;
    int h1 = cs0 + cs1 + cs2;
    int h2 = cs1 + cs2 + cs3;
    int h3 = cs2 + cs3 + csr;

    acc0 += (int)((unsigned)(h0 < 0 ? -h0 : h0) % PP);
    acc1 += (int)((unsigned)(h1 < 0 ? -h1 : h1) % PP);
    acc2 += (int)((unsigned)(h2 < 0 ? -h2 : h2) % PP);
    acc3 += (int)((unsigned)(h3 < 0 ? -h3 : h3) % PP);
  }
  // mean over 32 channels, exact in f32; trunc of nonneg == >>5
  const int i0 = acc0 >> 5, i1 = acc1 >> 5, i2 = acc2 >> 5, i3 = acc3 >> 5;

  const float4* t0 = (const float4*)(tp + (size_t)i0 * OUT);
  const float4* t1 = (const float4*)(tp + (size_t)i1 * OUT);
  const float4* t2 = (const float4*)(tp + (size_t)i2 * OUT);
  const float4* t3 = (const float4*)(tp + (size_t)i3 * OUT);

  float* ob = out + (size_t)b * OUT * HW + (size_t)y * WW + x0;
  #pragma unroll 4
  for (int k = 0; k < OUT / 4; ++k) {
    float4 va = t0[k], vb = t1[k], vc = t2[k], vd = t3[k];
    float* o0 = ob + (size_t)(4 * k) * HW;
    *(float4*)(o0)          = make_float4(va.x, vb.x, vc.x, vd.x);
    *(float4*)(o0 + HW)     = make_float4(va.y, vb.y, vc.y, vd.y);
    *(float4*)(o0 + 2 * HW) = make_float4(va.z, vb.z, vc.z, vd.z);
    *(float4*)(o0 + 3 * HW) = make_float4(va.w, vb.w, vc.w, vd.w);
  }
}

extern "C" void kernel_launch(void* const* d_in, const int* in_sizes, int n_in,
                              void* d_out, int out_size, void* d_ws, size_t ws_size,
                              hipStream_t stream) {
  const float* x     = (const float*)d_in[0];  // (4,32,512,512)
  const float* table = (const float*)d_in[1];  // (10000,64)
  const float* pw    = (const float*)d_in[2];  // (64,64)
  const float* pb    = (const float*)d_in[3];  // (64,)
  float* out = (float*)d_out;                  // (4,64,512,512)

  const int B = in_sizes[0] / (CH * HW);       // 4

  float* tp = (float*)d_ws;                    // PP*OUT*4 = 2.56 MB

  proj_table_kernel<<<PP / 4, 256, 0, stream>>>(table, pw, pb, tp);

  dim3 block(64, 4, 1);
  dim3 grid(WW / TWPX, HH / 4, B);             // (2, 128, 4)
  engram_kernel<<<grid, block, 0, stream>>>(x, tp, out);
}

// Round 8
// 111.004 us; speedup vs baseline: 1.6684x; 1.6684x over previous
//
#include <hip/hip_runtime.h>

// SpatialEngram: out[b,o,i,j] = (table @ proj_w.T + proj_b)[idx[b,i,j]][o]
// where idx = trunc(mean_c(abs(3x3_sum(trunc(x*100)))%P))
//
// Round 8: make the 268 MB write stream literally linear (fill-kernel-shaped).
//   K1 proj_kernel: tpT[o][p] = (table @ proj_w.T + proj_b)^T  (ws, 2.56 MB)
//   K2 idx_kernel:  integer path -> packed u16 idx[b][y][x]    (ws, 2 MB)
//   K3 expand2:     block = one (b, o, 64-row chunk). Stage tpT[o][:] (40 KB)
//                   in LDS, gather 4B/px from LDS, write 128 KB CONTIGUOUS
//                   region with nontemporal float4 stores (~7 TB/s pattern,
//                   proven by the harness fill dispatches).
//   Round-7 lesson kept: nontemporal stores mandatory (plain float4 = 185 us).

#define CH  32
#define HH  512
#define WW  512
#define EE  64
#define OUT 64
#define PP  10000

#define TWPX 256              // idx kernel: tile width in px (64 thr x 4 px)
#define HW   (HH * WW)        // 262144 = 2^18
#define CROWS 64              // expand2 chunk rows; 8 chunks per plane

typedef float f32x4 __attribute__((ext_vector_type(4)));

__global__ __launch_bounds__(256) void proj_kernel(
    const float* __restrict__ table, const float* __restrict__ pw,
    const float* __restrict__ pb, float* __restrict__ tpT) {
  __shared__ float sW[EE * OUT];          // sW[e*64 + o] = pw[o*64 + e]
  const int t = threadIdx.x;              // 0..255
  for (int i = t; i < EE * OUT; i += 256) {
    int o = i >> 6, e = i & 63;
    sW[e * OUT + o] = pw[i];
  }
  __syncthreads();
  const int o  = t & 63;
  const int pr = t >> 6;                  // 0..3
  const int p0 = blockIdx.x * 16 + pr;    // rows p0, p0+4, p0+8, p0+12
  const float4* r0 = (const float4*)(table + (size_t)(p0     ) * EE);
  const float4* r1 = (const float4*)(table + (size_t)(p0 +  4) * EE);
  const float4* r2 = (const float4*)(table + (size_t)(p0 +  8) * EE);
  const float4* r3 = (const float4*)(table + (size_t)(p0 + 12) * EE);
  float a0 = pb[o], a1 = pb[o], a2 = pb[o], a3 = pb[o];
  float b0 = 0.f,  b1 = 0.f,  b2 = 0.f,  b3 = 0.f;
  #pragma unroll
  for (int e4 = 0; e4 < EE / 4; ++e4) {
    float4 t0 = r0[e4], t1 = r1[e4], t2 = r2[e4], t3 = r3[e4];
    float w0 = sW[(4 * e4 + 0) * OUT + o];
    float w1 = sW[(4 * e4 + 1) * OUT + o];
    float w2 = sW[(4 * e4 + 2) * OUT + o];
    float w3 = sW[(4 * e4 + 3) * OUT + o];
    a0 = fmaf(t0.x, w0, a0); b0 = fmaf(t0.y, w1, b0);
    a0 = fmaf(t0.z, w2, a0); b0 = fmaf(t0.w, w3, b0);
    a1 = fmaf(t1.x, w0, a1); b1 = fmaf(t1.y, w1, b1);
    a1 = fmaf(t1.z, w2, a1); b1 = fmaf(t1.w, w3, b1);
    a2 = fmaf(t2.x, w0, a2); b2 = fmaf(t2.y, w1, b2);
    a2 = fmaf(t2.z, w2, a2); b2 = fmaf(t2.w, w3, b2);
    a3 = fmaf(t3.x, w0, a3); b3 = fmaf(t3.y, w1, b3);
    a3 = fmaf(t3.z, w2, a3); b3 = fmaf(t3.w, w3, b3);
  }
  float* oc = tpT + (size_t)o * PP;
  oc[p0]      = a0 + b0;
  oc[p0 + 4]  = a1 + b1;
  oc[p0 + 8]  = a2 + b2;
  oc[p0 + 12] = a3 + b3;
}

__device__ __forceinline__ int q3(float a, float b, float c) {
  // column sum of trunc(v*100) over 3 rows; (int) truncates toward zero
  return (int)(a * 100.0f) + (int)(b * 100.0f) + (int)(c * 100.0f);
}

__global__ __launch_bounds__(256) void idx_kernel(
    const float* __restrict__ x, unsigned short* __restrict__ idx16) {
  const int tx  = threadIdx.x;            // 0..63
  const int ty  = threadIdx.y;            // 0..3
  const int gx0 = blockIdx.x * TWPX;
  const int y   = blockIdx.y * 4 + ty;
  const int b   = blockIdx.z;
  const int x0  = gx0 + tx * 4;

  const int ym1 = max(y - 1, 0);
  const int yp1 = min(y + 1, HH - 1);
  const size_t rm1 = (size_t)ym1 * WW + x0;
  const size_t r0  = (size_t)y   * WW + x0;
  const size_t rp1 = (size_t)yp1 * WW + x0;

  const bool edge = (tx == 0) || (tx == 63);
  const int  ecol = (tx == 0) ? max(gx0 - 1, 0) : min(gx0 + TWPX, WW - 1);
  const size_t em1 = (size_t)ym1 * WW + ecol;
  const size_t e0  = (size_t)y   * WW + ecol;
  const size_t ep1 = (size_t)yp1 * WW + ecol;

  const float* xb = x + (size_t)b * CH * HW;

  int acc0 = 0, acc1 = 0, acc2 = 0, acc3 = 0;
  #pragma unroll 2
  for (int c = 0; c < CH; ++c) {
    const float* xc = xb + (size_t)c * HW;
    float4 a = *(const float4*)(xc + rm1);
    float4 m = *(const float4*)(xc + r0);
    float4 p = *(const float4*)(xc + rp1);

    int cs0 = q3(a.x, m.x, p.x);
    int cs1 = q3(a.y, m.y, p.y);
    int cs2 = q3(a.z, m.z, p.z);
    int cs3 = q3(a.w, m.w, p.w);

    int csl = __shfl(cs3, tx - 1, 64);    // junk for tx==0 (overwritten)
    int csr = __shfl(cs0, tx + 1, 64);    // junk for tx==63 (overwritten)
    if (edge) {
      int e = q3(xc[em1], xc[e0], xc[ep1]);
      if (tx == 0) csl = e; else csr = e;
    }

    int h0 = csl + cs0 + cs1;
    int h1 = cs0 + cs1 + cs2;
    int h2 = cs1 + cs2 + cs3;
    int h3 = cs2 + cs3 + csr;

    acc0 += (int)((unsigned)(h0 < 0 ? -h0 : h0) % PP);
    acc1 += (int)((unsigned)(h1 < 0 ? -h1 : h1) % PP);
    acc2 += (int)((unsigned)(h2 < 0 ? -h2 : h2) % PP);
    acc3 += (int)((unsigned)(h3 < 0 ? -h3 : h3) % PP);
  }
  // mean over 32 channels, exact in f32; trunc of nonneg == >>5
  const unsigned i0 = (unsigned)(acc0 >> 5), i1 = (unsigned)(acc1 >> 5);
  const unsigned i2 = (unsigned)(acc2 >> 5), i3 = (unsigned)(acc3 >> 5);

  const size_t pix = (size_t)b * HW + (size_t)y * WW + x0;
  uint2 pk = make_uint2(i0 | (i1 << 16), i2 | (i3 << 16));
  *(uint2*)(idx16 + pix) = pk;
}

__global__ __launch_bounds__(256) void expand2_kernel(
    const unsigned short* __restrict__ idx16, const float* __restrict__ tpT,
    float* __restrict__ out) {
  __shared__ float col[PP];                      // 40 KB -> 4 blocks/CU
  const int t = threadIdx.x;
  const unsigned bid   = blockIdx.x;             // b*512 + o*8 + chunk
  const int      chunk = bid & 7;
  const int      o     = (bid >> 3) & 63;
  const int      b     = bid >> 9;

  // stage this plane's projected-table column (contiguous 40 KB)
  const float4* src = (const float4*)(tpT + (size_t)o * PP);
  float4*       dst = (float4*)col;
  for (int i = t; i < PP / 4; i += 256) dst[i] = src[i];
  __syncthreads();

  const size_t pixbase = (size_t)chunk * (CROWS * WW);
  const unsigned short* ip = idx16 + (size_t)b * HW + pixbase;
  float* op = out + ((size_t)b * OUT + o) * HW + pixbase;

  const int iters = (CROWS * WW) / (256 * 4);    // 32
  #pragma unroll 4
  for (int it = 0; it < iters; ++it) {
    const int off = it * 1024 + t * 4;
    const uint2 pk = *(const uint2*)(ip + off);
    const unsigned i0 = pk.x & 0xFFFFu, i1 = pk.x >> 16;
    const unsigned i2 = pk.y & 0xFFFFu, i3 = pk.y >> 16;
    f32x4 v = { col[i0], col[i1], col[i2], col[i3] };
    __builtin_nontemporal_store(v, (f32x4*)(op + off));
  }
}

extern "C" void kernel_launch(void* const* d_in, const int* in_sizes, int n_in,
                              void* d_out, int out_size, void* d_ws, size_t ws_size,
                              hipStream_t stream) {
  const float* x     = (const float*)d_in[0];  // (4,32,512,512)
  const float* table = (const float*)d_in[1];  // (10000,64)
  const float* pw    = (const float*)d_in[2];  // (64,64)
  const float* pb    = (const float*)d_in[3];  // (64,)
  float* out = (float*)d_out;                  // (4,64,512,512)

  const int B = in_sizes[0] / (CH * HW);       // 4

  float* tpT = (float*)d_ws;                                        // 2.56 MB
  unsigned short* idx16 =
      (unsigned short*)((char*)d_ws + (size_t)OUT * PP * 4);        // 2 MB

  proj_kernel<<<PP / 16, 256, 0, stream>>>(table, pw, pb, tpT);

  dim3 block(64, 4, 1);
  dim3 grid(WW / TWPX, HH / 4, B);             // (2, 128, 4)
  idx_kernel<<<grid, block, 0, stream>>>(x, idx16);

  const int nblk = B * OUT * (HH / CROWS);     // 4*64*8 = 2048
  expand2_kernel<<<nblk, 256, 0, stream>>>(idx16, tpT, out);
}